// Round 16
// baseline (151.925 us; speedup 1.0000x reference)
//
#include <hip/hip_runtime.h>
#include <math.h>

// n=16384 Gaussian points in 3D. Exact 12-NN (incl self) per point:
//   out[i] = b + ( (W·p_i)·(1 + 11/sqrt(2)) + 0.5 * sum_{11NN} W·|p_i - p_j| ) / 12
//
// R16: 3 dispatches (session model: ~10 µs/dispatch gap + kernel time):
//   memset(hist+cnt) -> ONE fused wide sort (64 blocks: global-atomic hist ->
//   gbar -> 3-axis LDS scan on blocks 0..2 -> gbar -> scatter) -> query.
// Query logic = R13/R14/R15 thrice-verified path (one wave per query, best
// axis by max |coord|, seed 768 -> u = 12th of 64 lane minima -> extent from
// prefix sums -> 4-deep paired collect -> 12-round paired knockout; rare
// wave-uniform med3 fallback). Reshaped to 256 blocks x 1024 thr (16 waves,
// 1 block/CU, fully resident), each wave serially does 4 interleaved queries
// (t = k*4096 + wgid) — occupancy probe; per-query semantics unchanged.

#define NBINS  2048
#define CMIN_  (-6.0f)
#define INVBW_ ((float)NBINS / 12.0f)
#define SORTB  64
#define QBLK   1024
#define QGRID  256
#define SEED   768
#define KK     12
#define CD     4
#define BIG    3.0e38f

__device__ __forceinline__ int bin_of(float x) {
  int b = (int)((x - CMIN_) * INVBW_);
  b = b < 0 ? 0 : b;
  b = b > NBINS - 1 ? NBINS - 1 : b;
  return b;
}

// device-scope spin barrier; 64 small blocks are trivially co-resident
__device__ __forceinline__ void gbar(int* c, int target) {
  __syncthreads();
  if (threadIdx.x == 0) {
    __threadfence();
    atomicAdd(c, 1);
    while (atomicAdd(c, 0) < target) __builtin_amdgcn_s_sleep(2);
    __threadfence();
  }
  __syncthreads();
}

__device__ __forceinline__ float wave_min(float v) {
#pragma unroll
  for (int o = 1; o < 64; o <<= 1) v = fminf(v, __shfl_xor(v, o));
  return v;
}

// sorted ascending 4-deep paired insert (static indexing -> registers)
__device__ __forceinline__ void ins4(float (&qd)[CD], float (&qw)[CD],
                                     float d, float w) {
#pragma unroll
  for (int k = CD - 1; k >= 1; --k) {
    const bool up  = (qd[k - 1] > d);
    const bool mid = (qd[k] > d);
    const float nd = up ? qd[k - 1] : (mid ? d : qd[k]);
    const float nw = up ? qw[k - 1] : (mid ? w : qw[k]);
    qd[k] = nd; qw[k] = nw;
  }
  if (qd[0] > d) { qw[0] = w; qd[0] = d; }
}

// ---------------- K1: fused 3-axis sort (64 blocks, 2 gbar barriers) ---------
// cursorEnd[b] = end of bin b (query-side); scatCur[b] = start (scatter-side).
__global__ __launch_bounds__(256)
void sort64_kernel(const float* __restrict__ p, int* __restrict__ hist,
                   int* __restrict__ cursorEnd, int* __restrict__ scatCur,
                   int* __restrict__ cnt, float4* __restrict__ s_all, int n) {
  __shared__ int ssum[256];
  const int tid = threadIdx.x;
  const int gid = blockIdx.x * 256 + tid;          // 0..16383, 1 point/thread

  // ---- hist: 3 global atomics per point (6144 lines, no hot line) ----
  float x, y, z;
  if (gid < n) {
    x = p[3 * gid]; y = p[3 * gid + 1]; z = p[3 * gid + 2];
    atomicAdd(&hist[bin_of(x)], 1);
    atomicAdd(&hist[NBINS + bin_of(y)], 1);
    atomicAdd(&hist[2 * NBINS + bin_of(z)], 1);
  }
  gbar(&cnt[0], SORTB);

  // ---- scan: blocks 0..2, one axis each (256 thr x 8 bins) ----
  if (blockIdx.x < 3) {
    const int dim = blockIdx.x;
    const int* __restrict__ h = hist + dim * NBINS;
    int* __restrict__ ce = cursorEnd + dim * NBINS;
    int* __restrict__ sc = scatCur + dim * NBINS;
    const int base = tid * (NBINS / 256);
    int v[NBINS / 256];
    int sum = 0;
#pragma unroll
    for (int t = 0; t < NBINS / 256; ++t) { v[t] = h[base + t]; sum += v[t]; }
    ssum[tid] = sum;
    __syncthreads();
    for (int off = 1; off < 256; off <<= 1) {
      const int a = (tid >= off) ? ssum[tid - off] : 0;
      __syncthreads();
      ssum[tid] += a;
      __syncthreads();
    }
    int run = (tid > 0) ? ssum[tid - 1] : 0;
#pragma unroll
    for (int t = 0; t < NBINS / 256; ++t) {
      sc[base + t] = run;
      run += v[t];
      ce[base + t] = run;
    }
  }
  gbar(&cnt[1], SORTB);

  // ---- scatter: 3 axes per point ----
  if (gid < n) {
    const float4 v = make_float4(x, y, z, __int_as_float(gid));
    const int px = atomicAdd(&scatCur[bin_of(x)], 1);
    const int py = atomicAdd(&scatCur[NBINS + bin_of(y)], 1);
    const int pz = atomicAdd(&scatCur[2 * NBINS + bin_of(z)], 1);
    s_all[px] = v;
    s_all[n + py] = v;
    s_all[2 * n + pz] = v;
  }
}

// ---------------- K2: query (16 waves/block, 4 queries/wave) -----------------
__global__ __launch_bounds__(QBLK)
void query_kernel(const float4* __restrict__ sx, const float4* __restrict__ sy,
                  const float4* __restrict__ sz, const int* __restrict__ cx,
                  const int* __restrict__ cy, const int* __restrict__ cz,
                  const float* __restrict__ W, const float* __restrict__ bias,
                  float* __restrict__ out, int n) {
  const int lane = threadIdx.x & 63;
  const int wgid = blockIdx.x * (QBLK / 64) + (threadIdx.x >> 6);  // 0..4095
  const float W0 = W[0], W1 = W[1], W2 = W[2];
  const float bb = bias[0];

#pragma unroll 1
  for (int k = 0; k < 4; ++k) {
    const int t = k * 4096 + wgid;                 // interleaved queries

    const float4 me = sx[t];                       // enumerate via x-sorted
    const float xi = me.x, yi = me.y, zi = me.z;
    const int orig = __float_as_int(me.w);

    // ---- choose axis with max |coord| (wave-uniform) ----
    const float ax = fabsf(xi), ay = fabsf(yi), az = fabsf(zi);
    const float4* sv; const int* cur; float cq;
    if (ay >= ax && ay >= az)      { sv = sy; cur = cy; cq = yi; }
    else if (az >= ax && az >= ay) { sv = sz; cur = cz; cq = zi; }
    else                           { sv = sx; cur = cx; cq = xi; }

    // ---- bin-estimated rank -> seed window ----
    const int bq = bin_of(cq);
    const int bs = (bq > 0) ? cur[bq - 1] : 0;
    const int be = cur[bq];
    int lo = ((bs + be) >> 1) - SEED / 2;
    lo = lo < 0 ? 0 : lo;
    lo = lo > n - SEED ? n - SEED : lo;
    const float4* base = sv + lo + lane;

    // ---- 1. seed lane-minima ----
    float m = BIG;
#pragma unroll
    for (int s = 0; s < SEED / 64; ++s) {
      const float4 c = base[s * 64];
      const float dx = xi - c.x, dy = yi - c.y, dz = zi - c.z;
      m = fminf(m, fmaf(dx, dx, fmaf(dy, dy, dz * dz)));
    }

    // ---- 2. u = 12th smallest of the 64 lane minima ----
    float u;
    {
      float v = m;
#pragma unroll
      for (int r = 0; r < KK; ++r) {
        const float mm = wave_min(v);
        u = mm;
        v = (v == mm) ? BIG : v;
      }
    }

    // ---- 3. extent from prefix sums: {|c - cq| <= sqrt(u)} ⊆ [lo2, hi2) ----
    const float s = sqrtf(u);
    const int bl = bin_of(cq - s);
    const int bh = bin_of(cq + s);
    const int lo2 = (bl > 0) ? cur[bl - 1] : 0;
    const int hi2 = cur[bh];
    const int steps = (hi2 - lo2 + 63) >> 6;

    // ---- collect-scan: fixed-trip, break-free ----
    float qd[CD], qw[CD];
    int ccnt = 0;
#pragma unroll
    for (int kk = 0; kk < CD; ++kk) { qd[kk] = BIG; qw[kk] = 0.f; }

    int st = 0;
    for (; st + 2 <= steps; st += 2) {
      const int p0 = lo2 + st * 64 + lane;
      const int p1 = p0 + 64;
      const float4 c0 = sv[p0];
      const float4 c1 = sv[(p1 < hi2) ? p1 : hi2 - 1];
      {
        const float dx = xi - c0.x, dy = yi - c0.y, dz = zi - c0.z;
        const float d2 = fmaf(dx, dx, fmaf(dy, dy, dz * dz));
        if (d2 <= u) {
          const float w = fmaf(W0, fabsf(dx), fmaf(W1, fabsf(dy), W2 * fabsf(dz)));
          ++ccnt; ins4(qd, qw, d2, w);
        }
      }
      if (p1 < hi2) {
        const float dx = xi - c1.x, dy = yi - c1.y, dz = zi - c1.z;
        const float d2 = fmaf(dx, dx, fmaf(dy, dy, dz * dz));
        if (d2 <= u) {
          const float w = fmaf(W0, fabsf(dx), fmaf(W1, fabsf(dy), W2 * fabsf(dz)));
          ++ccnt; ins4(qd, qw, d2, w);
        }
      }
    }
    for (; st < steps; ++st) {
      const int pos = lo2 + st * 64 + lane;
      if (pos < hi2) {
        const float4 c = sv[pos];
        const float dx = xi - c.x, dy = yi - c.y, dz = zi - c.z;
        const float d2 = fmaf(dx, dx, fmaf(dy, dy, dz * dz));
        if (d2 <= u) {
          const float w = fmaf(W0, fabsf(dx), fmaf(W1, fabsf(dy), W2 * fabsf(dz)));
          ++ccnt; ins4(qd, qw, d2, w);
        }
      }
    }

    // ---- 4. extract exact 12 smallest ----
    float acc = 0.f;
    const bool ovf = __ballot(ccnt > CD) != 0ULL;   // wave-uniform
    if (!ovf) {
#pragma unroll
      for (int r = 0; r < KK; ++r) {
        const float mm = wave_min(qd[0]);
        const unsigned long long bal = __ballot(qd[0] == mm);
        if (qd[0] == mm && lane == (int)(__ffsll(bal) - 1)) {
          acc += qw[0];
#pragma unroll
          for (int kk = 0; kk < CD - 1; ++kk) { qd[kk] = qd[kk + 1]; qw[kk] = qw[kk + 1]; }
          qd[CD - 1] = BIG;
        }
      }
    } else {
      // rare exact fallback over the same extent: med3 top-12 -> tau -> rescan
      float dd[KK];
#pragma unroll
      for (int kk = 0; kk < KK; ++kk) dd[kk] = BIG;
      for (int s0 = 0; s0 < steps; ++s0) {
        const int pos = lo2 + s0 * 64 + lane;
        const float4 c = sv[(pos < hi2) ? pos : hi2 - 1];
        const float dx = xi - c.x, dy = yi - c.y, dz = zi - c.z;
        const float d2 = (pos < hi2) ? fmaf(dx, dx, fmaf(dy, dy, dz * dz)) : BIG;
#pragma unroll
        for (int kk = KK - 1; kk >= 1; --kk)
          dd[kk] = __builtin_amdgcn_fmed3f(d2, dd[kk - 1], dd[kk]);
        dd[0] = fminf(dd[0], d2);
      }
      float tau = 0.f;
#pragma unroll
      for (int r = 0; r < KK; ++r) {
        const float mm = wave_min(dd[0]);
        if (dd[0] == mm) {
#pragma unroll
          for (int kk = 0; kk < KK - 1; ++kk) dd[kk] = dd[kk + 1];
          dd[KK - 1] = BIG;
        }
        tau = mm;
      }
      for (int s0 = 0; s0 < steps; ++s0) {
        const int pos = lo2 + s0 * 64 + lane;
        if (pos < hi2) {
          const float4 c = sv[pos];
          const float dx = xi - c.x, dy = yi - c.y, dz = zi - c.z;
          const float d2 = fmaf(dx, dx, fmaf(dy, dy, dz * dz));
          const float w  = fmaf(W0, fabsf(dx), fmaf(W1, fabsf(dy), W2 * fabsf(dz)));
          acc += (d2 <= tau) ? w : 0.f;
        }
      }
    }

    // ---- 5. reduce + write ----
#pragma unroll
    for (int o = 1; o < 64; o <<= 1) acc += __shfl_xor(acc, o);
    if (lane == 0) {
      const float xw0 = W0 * xi + W1 * yi + W2 * zi;
      // 1 + 11/sqrt(2)
      out[orig] = bb + (xw0 * 8.778174593052022f + 0.5f * acc) * (1.0f / 12.0f);
    }
  }
}

extern "C" void kernel_launch(void* const* d_in, const int* in_sizes, int n_in,
                              void* d_out, int out_size, void* d_ws, size_t ws_size,
                              hipStream_t stream) {
  const float* p  = (const float*)d_in[0];
  const float* W  = (const float*)d_in[1];
  const float* bb = (const float*)d_in[2];
  float* out = (float*)d_out;

  const int n = in_sizes[0] / 3;   // 16384

  // ws: hist 3x2048 @0 | cnt[16] @24576 | cursorEnd 3x2048 @24640
  //     | scatCur 3x2048 @49216 | sorted 3xn float4 @73792
  int*    hist      = (int*)d_ws;
  int*    cnt       = (int*)((char*)d_ws + 24576);
  int*    cursorEnd = (int*)((char*)d_ws + 24640);
  int*    scatCur   = (int*)((char*)d_ws + 49216);
  float4* s_all     = (float4*)((char*)d_ws + 73792);

  int*    cx = cursorEnd;
  int*    cy = cx + NBINS;
  int*    cz = cy + NBINS;
  float4* sx = s_all;
  float4* sy = sx + n;
  float4* sz = sy + n;

  hipMemsetAsync(d_ws, 0, 24640, stream);   // hist + cnt
  sort64_kernel<<<SORTB, 256, 0, stream>>>(p, hist, cursorEnd, scatCur, cnt, s_all, n);
  query_kernel<<<QGRID, QBLK, 0, stream>>>(sx, sy, sz, cx, cy, cz, W, bb, out, n);
}

// Round 17
// 143.536 us; speedup vs baseline: 1.0584x; 1.0584x over previous
//
#include <hip/hip_runtime.h>
#include <math.h>

// n=16384 Gaussian points in 3D. Exact 12-NN (incl self) per point:
//   out[i] = b + ( (W·p_i)·(1 + 11/sqrt(2)) + 0.5 * sum_{11NN} W·|p_i - p_j| ) / 12
//
// R17: TWO dispatches.
//   K1: self-zeroing fused 3-axis counting sort, 64 co-resident blocks,
//       3 gbar barriers (zero -> hist -> scan -> scatter). R9-proven pattern.
//   K2: query EXACTLY as R13/R14/R15 (thrice-verified 67 µs): 4096 blocks x
//       256 thr = 16384 waves, ONE query per wave (R16's 4096-wave reshape
//       lost 4x parallelism -> reverted). Per query: best axis by max |coord|
//       (min slab mass -> ~uniform extents); seed 768 around bin-estimated
//       rank -> per-lane min d2 -> u = 12th of 64 lane minima (valid UB of
//       tau) -> extent from prefix sums -> fixed-trip collect into 4-deep
//       paired (d2,w) buffer -> 12-round paired knockout (exact take-12,
//       first-lane tie-break) -> reduce, write. Overflow (rare, wave-uniform)
//       -> exact med3 fallback over the same extent. Self contributes w=0.

#define NBINS  2048
#define CMIN_  (-6.0f)
#define INVBW_ ((float)NBINS / 12.0f)
#define SORTB  64
#define BLOCK  256
#define WPB    4
#define SEED   768
#define KK     12
#define CD     4
#define BIG    3.0e38f

__device__ __forceinline__ int bin_of(float x) {
  int b = (int)((x - CMIN_) * INVBW_);
  b = b < 0 ? 0 : b;
  b = b > NBINS - 1 ? NBINS - 1 : b;
  return b;
}

// device-scope spin barrier; 64 small blocks are trivially co-resident
__device__ __forceinline__ void gbar(int* c, int target) {
  __syncthreads();
  if (threadIdx.x == 0) {
    __threadfence();
    atomicAdd(c, 1);
    while (atomicAdd(c, 0) < target) __builtin_amdgcn_s_sleep(2);
    __threadfence();
  }
  __syncthreads();
}

__device__ __forceinline__ float wave_min(float v) {
#pragma unroll
  for (int o = 1; o < 64; o <<= 1) v = fminf(v, __shfl_xor(v, o));
  return v;
}

// sorted ascending 4-deep paired insert (static indexing -> registers)
__device__ __forceinline__ void ins4(float (&qd)[CD], float (&qw)[CD],
                                     float d, float w) {
#pragma unroll
  for (int k = CD - 1; k >= 1; --k) {
    const bool up  = (qd[k - 1] > d);
    const bool mid = (qd[k] > d);
    const float nd = up ? qd[k - 1] : (mid ? d : qd[k]);
    const float nw = up ? qw[k - 1] : (mid ? w : qw[k]);
    qd[k] = nd; qw[k] = nw;
  }
  if (qd[0] > d) { qw[0] = w; qd[0] = d; }
}

// ---------------- K1: self-zeroing fused 3-axis sort (64 blocks) -------------
// cursorEnd[b] = end of bin b (query-side); scatCur[b] = start (scatter-side).
__global__ __launch_bounds__(256)
void sort64_kernel(const float* __restrict__ p, int* __restrict__ hist,
                   int* __restrict__ cursorEnd, int* __restrict__ scatCur,
                   int* __restrict__ cnt, float4* __restrict__ s_all, int n) {
  __shared__ int ssum[256];
  const int tid = threadIdx.x;
  const int gid = blockIdx.x * 256 + tid;          // 0..16383, 1 point/thread

  // ---- zero hist (24 KB over 16384 threads) ----
  if (gid < 3 * NBINS) hist[gid] = 0;
  gbar(&cnt[0], SORTB);

  // ---- hist: 3 global atomics per point (6144 lines, no hot line) ----
  float x, y, z;
  if (gid < n) {
    x = p[3 * gid]; y = p[3 * gid + 1]; z = p[3 * gid + 2];
    atomicAdd(&hist[bin_of(x)], 1);
    atomicAdd(&hist[NBINS + bin_of(y)], 1);
    atomicAdd(&hist[2 * NBINS + bin_of(z)], 1);
  }
  gbar(&cnt[1], SORTB);

  // ---- scan: blocks 0..2, one axis each (256 thr x 8 bins) ----
  if (blockIdx.x < 3) {
    const int dim = blockIdx.x;
    const int* __restrict__ h = hist + dim * NBINS;
    int* __restrict__ ce = cursorEnd + dim * NBINS;
    int* __restrict__ sc = scatCur + dim * NBINS;
    const int base = tid * (NBINS / 256);
    int v[NBINS / 256];
    int sum = 0;
#pragma unroll
    for (int t = 0; t < NBINS / 256; ++t) { v[t] = h[base + t]; sum += v[t]; }
    ssum[tid] = sum;
    __syncthreads();
    for (int off = 1; off < 256; off <<= 1) {
      const int a = (tid >= off) ? ssum[tid - off] : 0;
      __syncthreads();
      ssum[tid] += a;
      __syncthreads();
    }
    int run = (tid > 0) ? ssum[tid - 1] : 0;
#pragma unroll
    for (int t = 0; t < NBINS / 256; ++t) {
      sc[base + t] = run;
      run += v[t];
      ce[base + t] = run;
    }
  }
  gbar(&cnt[2], SORTB);

  // ---- scatter: 3 axes per point ----
  if (gid < n) {
    const float4 v = make_float4(x, y, z, __int_as_float(gid));
    const int px = atomicAdd(&scatCur[bin_of(x)], 1);
    const int py = atomicAdd(&scatCur[NBINS + bin_of(y)], 1);
    const int pz = atomicAdd(&scatCur[2 * NBINS + bin_of(z)], 1);
    s_all[px] = v;
    s_all[n + py] = v;
    s_all[2 * n + pz] = v;
  }
}

// ---------------- K2: query (one wave per query, best-axis extent) -----------
__global__ __launch_bounds__(BLOCK)
void query_kernel(const float4* __restrict__ sx, const float4* __restrict__ sy,
                  const float4* __restrict__ sz, const int* __restrict__ cx,
                  const int* __restrict__ cy, const int* __restrict__ cz,
                  const float* __restrict__ W, const float* __restrict__ bias,
                  float* __restrict__ out, int n) {
  const int lane = threadIdx.x & 63;
  const int wv   = threadIdx.x >> 6;
  const int t    = wv * (n >> 2) + blockIdx.x;     // quartile interleave
  const float W0 = W[0], W1 = W[1], W2 = W[2];
  const float bb = bias[0];

  const float4 me = sx[t];                          // enumerate via x-sorted
  const float xi = me.x, yi = me.y, zi = me.z;
  const int orig = __float_as_int(me.w);

  // ---- choose axis with max |coord| (wave-uniform) ----
  const float ax = fabsf(xi), ay = fabsf(yi), az = fabsf(zi);
  const float4* sv; const int* cur; float cq;
  if (ay >= ax && ay >= az)      { sv = sy; cur = cy; cq = yi; }
  else if (az >= ax && az >= ay) { sv = sz; cur = cz; cq = zi; }
  else                           { sv = sx; cur = cx; cq = xi; }

  // ---- bin-estimated rank -> seed window ----
  const int bq = bin_of(cq);
  const int bs = (bq > 0) ? cur[bq - 1] : 0;
  const int be = cur[bq];
  int lo = ((bs + be) >> 1) - SEED / 2;
  lo = lo < 0 ? 0 : lo;
  lo = lo > n - SEED ? n - SEED : lo;
  const float4* base = sv + lo + lane;

  // ---- 1. seed lane-minima ----
  float m = BIG;
#pragma unroll
  for (int s = 0; s < SEED / 64; ++s) {
    const float4 c = base[s * 64];
    const float dx = xi - c.x, dy = yi - c.y, dz = zi - c.z;
    m = fminf(m, fmaf(dx, dx, fmaf(dy, dy, dz * dz)));
  }

  // ---- 2. u = 12th smallest of the 64 lane minima ----
  float u;
  {
    float v = m;
#pragma unroll
    for (int r = 0; r < KK; ++r) {
      const float mm = wave_min(v);
      u = mm;
      v = (v == mm) ? BIG : v;
    }
  }

  // ---- 3. extent from prefix sums: {|c - cq| <= sqrt(u)} ⊆ [lo2, hi2) ----
  const float s = sqrtf(u);
  const int bl = bin_of(cq - s);
  const int bh = bin_of(cq + s);
  const int lo2 = (bl > 0) ? cur[bl - 1] : 0;
  const int hi2 = cur[bh];
  const int steps = (hi2 - lo2 + 63) >> 6;

  // ---- collect-scan: fixed-trip, break-free ----
  float qd[CD], qw[CD];
  int ccnt = 0;
#pragma unroll
  for (int k = 0; k < CD; ++k) { qd[k] = BIG; qw[k] = 0.f; }

  int st = 0;
  for (; st + 2 <= steps; st += 2) {
    const int p0 = lo2 + st * 64 + lane;
    const int p1 = p0 + 64;
    const float4 c0 = sv[p0];
    const float4 c1 = sv[(p1 < hi2) ? p1 : hi2 - 1];
    {
      const float dx = xi - c0.x, dy = yi - c0.y, dz = zi - c0.z;
      const float d2 = fmaf(dx, dx, fmaf(dy, dy, dz * dz));
      if (d2 <= u) {
        const float w = fmaf(W0, fabsf(dx), fmaf(W1, fabsf(dy), W2 * fabsf(dz)));
        ++ccnt; ins4(qd, qw, d2, w);
      }
    }
    if (p1 < hi2) {
      const float dx = xi - c1.x, dy = yi - c1.y, dz = zi - c1.z;
      const float d2 = fmaf(dx, dx, fmaf(dy, dy, dz * dz));
      if (d2 <= u) {
        const float w = fmaf(W0, fabsf(dx), fmaf(W1, fabsf(dy), W2 * fabsf(dz)));
        ++ccnt; ins4(qd, qw, d2, w);
      }
    }
  }
  for (; st < steps; ++st) {
    const int pos = lo2 + st * 64 + lane;
    if (pos < hi2) {
      const float4 c = sv[pos];
      const float dx = xi - c.x, dy = yi - c.y, dz = zi - c.z;
      const float d2 = fmaf(dx, dx, fmaf(dy, dy, dz * dz));
      if (d2 <= u) {
        const float w = fmaf(W0, fabsf(dx), fmaf(W1, fabsf(dy), W2 * fabsf(dz)));
        ++ccnt; ins4(qd, qw, d2, w);
      }
    }
  }

  // ---- 4. extract exact 12 smallest ----
  float acc = 0.f;
  const bool ovf = __ballot(ccnt > CD) != 0ULL;   // wave-uniform
  if (!ovf) {
#pragma unroll
    for (int r = 0; r < KK; ++r) {
      const float mm = wave_min(qd[0]);
      const unsigned long long bal = __ballot(qd[0] == mm);
      if (qd[0] == mm && lane == (int)(__ffsll(bal) - 1)) {
        acc += qw[0];
#pragma unroll
        for (int k = 0; k < CD - 1; ++k) { qd[k] = qd[k + 1]; qw[k] = qw[k + 1]; }
        qd[CD - 1] = BIG;
      }
    }
  } else {
    // rare exact fallback over the same extent: med3 top-12 -> tau -> rescan
    float dd[KK];
#pragma unroll
    for (int k = 0; k < KK; ++k) dd[k] = BIG;
    for (int s0 = 0; s0 < steps; ++s0) {
      const int pos = lo2 + s0 * 64 + lane;
      const float4 c = sv[(pos < hi2) ? pos : hi2 - 1];
      const float dx = xi - c.x, dy = yi - c.y, dz = zi - c.z;
      const float d2 = (pos < hi2) ? fmaf(dx, dx, fmaf(dy, dy, dz * dz)) : BIG;
#pragma unroll
      for (int k = KK - 1; k >= 1; --k)
        dd[k] = __builtin_amdgcn_fmed3f(d2, dd[k - 1], dd[k]);
      dd[0] = fminf(dd[0], d2);
    }
    float tau = 0.f;
#pragma unroll
    for (int r = 0; r < KK; ++r) {
      const float mm = wave_min(dd[0]);
      if (dd[0] == mm) {
#pragma unroll
        for (int k = 0; k < KK - 1; ++k) dd[k] = dd[k + 1];
        dd[KK - 1] = BIG;
      }
      tau = mm;
    }
    for (int s0 = 0; s0 < steps; ++s0) {
      const int pos = lo2 + s0 * 64 + lane;
      if (pos < hi2) {
        const float4 c = sv[pos];
        const float dx = xi - c.x, dy = yi - c.y, dz = zi - c.z;
        const float d2 = fmaf(dx, dx, fmaf(dy, dy, dz * dz));
        const float w  = fmaf(W0, fabsf(dx), fmaf(W1, fabsf(dy), W2 * fabsf(dz)));
        acc += (d2 <= tau) ? w : 0.f;
      }
    }
  }

  // ---- 5. reduce + write ----
#pragma unroll
  for (int o = 1; o < 64; o <<= 1) acc += __shfl_xor(acc, o);
  if (lane == 0) {
    const float xw0 = W0 * xi + W1 * yi + W2 * zi;
    // 1 + 11/sqrt(2)
    out[orig] = bb + (xw0 * 8.778174593052022f + 0.5f * acc) * (1.0f / 12.0f);
  }
}

extern "C" void kernel_launch(void* const* d_in, const int* in_sizes, int n_in,
                              void* d_out, int out_size, void* d_ws, size_t ws_size,
                              hipStream_t stream) {
  const float* p  = (const float*)d_in[0];
  const float* W  = (const float*)d_in[1];
  const float* bb = (const float*)d_in[2];
  float* out = (float*)d_out;

  const int n = in_sizes[0] / 3;   // 16384

  // ws: hist 3x2048 @0 | cnt[16] @24576 | cursorEnd 3x2048 @24640
  //     | scatCur 3x2048 @49216 | sorted 3xn float4 @73792
  int*    hist      = (int*)d_ws;
  int*    cnt       = (int*)((char*)d_ws + 24576);
  int*    cursorEnd = (int*)((char*)d_ws + 24640);
  int*    scatCur   = (int*)((char*)d_ws + 49216);
  float4* s_all     = (float4*)((char*)d_ws + 73792);

  int*    cx = cursorEnd;
  int*    cy = cx + NBINS;
  int*    cz = cy + NBINS;
  float4* sx = s_all;
  float4* sy = sx + n;
  float4* sz = sy + n;

  // cnt must be zero before K1: harness re-poisons ws with 0xAA, so zero it
  // with a tiny async memset folded into... no extra dispatch allowed? It IS
  // allowed (hipMemsetAsync on stream is graph-safe); 64 B only.
  hipMemsetAsync(cnt, 0, 64, stream);
  sort64_kernel<<<SORTB, 256, 0, stream>>>(p, hist, cursorEnd, scatCur, cnt, s_all, n);
  query_kernel<<<n / WPB, BLOCK, 0, stream>>>(sx, sy, sz, cx, cy, cz, W, bb, out, n);
}

// Round 18
// 136.942 us; speedup vs baseline: 1.1094x; 1.0482x over previous
//
#include <hip/hip_runtime.h>
#include <math.h>

// n=16384 Gaussian points in 3D. Exact 12-NN (incl self) per point:
//   out[i] = b + ( (W·p_i)·(1 + 11/sqrt(2)) + 0.5 * sum_{11NN} W·|p_i - p_j| ) / 12
//
// R18: sort = R16's best-measured structure (memset(hist+cnt) -> ONE fused
// 64-block sort with 2 gbar barriers: hist -> scan -> scatter). Query = the
// 4x-verified R13 kernel (4096 blocks x 256, one wave per query, best-axis
// extent) with ONE change: COUNT-DOWN extraction. Sum all collected w, wave-
// sum ccnt -> C, then remove only the r = C-12 LARGEST entries (r ~ 1-3)
// instead of 12-round min-select. Exact: collected ⊇ true top-12 (else
// overflow fallback), removing the r largest leaves exactly the 12 smallest;
// self (d2=0,w=0) never removed; ties first-lane; r>8 -> original select.

#define NBINS  2048
#define CMIN_  (-6.0f)
#define INVBW_ ((float)NBINS / 12.0f)
#define SORTB  64
#define BLOCK  256
#define WPB    4
#define SEED   768
#define KK     12
#define CD     4
#define BIG    3.0e38f

__device__ __forceinline__ int bin_of(float x) {
  int b = (int)((x - CMIN_) * INVBW_);
  b = b < 0 ? 0 : b;
  b = b > NBINS - 1 ? NBINS - 1 : b;
  return b;
}

// device-scope spin barrier; 64 small blocks are trivially co-resident
__device__ __forceinline__ void gbar(int* c, int target) {
  __syncthreads();
  if (threadIdx.x == 0) {
    __threadfence();
    atomicAdd(c, 1);
    while (atomicAdd(c, 0) < target) __builtin_amdgcn_s_sleep(2);
    __threadfence();
  }
  __syncthreads();
}

__device__ __forceinline__ float wave_min(float v) {
#pragma unroll
  for (int o = 1; o < 64; o <<= 1) v = fminf(v, __shfl_xor(v, o));
  return v;
}

__device__ __forceinline__ float wave_max(float v) {
#pragma unroll
  for (int o = 1; o < 64; o <<= 1) v = fmaxf(v, __shfl_xor(v, o));
  return v;
}

// sorted ascending 4-deep paired insert (static indexing -> registers)
__device__ __forceinline__ void ins4(float (&qd)[CD], float (&qw)[CD],
                                     float d, float w) {
#pragma unroll
  for (int k = CD - 1; k >= 1; --k) {
    const bool up  = (qd[k - 1] > d);
    const bool mid = (qd[k] > d);
    const float nd = up ? qd[k - 1] : (mid ? d : qd[k]);
    const float nw = up ? qw[k - 1] : (mid ? w : qw[k]);
    qd[k] = nd; qw[k] = nw;
  }
  if (qd[0] > d) { qw[0] = w; qd[0] = d; }
}

// ---------------- K1: fused 3-axis sort (64 blocks, 2 gbar barriers) ---------
// cursorEnd[b] = end of bin b (query-side); scatCur[b] = start (scatter-side).
__global__ __launch_bounds__(256)
void sort64_kernel(const float* __restrict__ p, int* __restrict__ hist,
                   int* __restrict__ cursorEnd, int* __restrict__ scatCur,
                   int* __restrict__ cnt, float4* __restrict__ s_all, int n) {
  __shared__ int ssum[256];
  const int tid = threadIdx.x;
  const int gid = blockIdx.x * 256 + tid;          // 0..16383, 1 point/thread

  // ---- hist: 3 global atomics per point (6144 lines, no hot line) ----
  float x, y, z;
  if (gid < n) {
    x = p[3 * gid]; y = p[3 * gid + 1]; z = p[3 * gid + 2];
    atomicAdd(&hist[bin_of(x)], 1);
    atomicAdd(&hist[NBINS + bin_of(y)], 1);
    atomicAdd(&hist[2 * NBINS + bin_of(z)], 1);
  }
  gbar(&cnt[0], SORTB);

  // ---- scan: blocks 0..2, one axis each (256 thr x 8 bins) ----
  if (blockIdx.x < 3) {
    const int dim = blockIdx.x;
    const int* __restrict__ h = hist + dim * NBINS;
    int* __restrict__ ce = cursorEnd + dim * NBINS;
    int* __restrict__ sc = scatCur + dim * NBINS;
    const int base = tid * (NBINS / 256);
    int v[NBINS / 256];
    int sum = 0;
#pragma unroll
    for (int t = 0; t < NBINS / 256; ++t) { v[t] = h[base + t]; sum += v[t]; }
    ssum[tid] = sum;
    __syncthreads();
    for (int off = 1; off < 256; off <<= 1) {
      const int a = (tid >= off) ? ssum[tid - off] : 0;
      __syncthreads();
      ssum[tid] += a;
      __syncthreads();
    }
    int run = (tid > 0) ? ssum[tid - 1] : 0;
#pragma unroll
    for (int t = 0; t < NBINS / 256; ++t) {
      sc[base + t] = run;
      run += v[t];
      ce[base + t] = run;
    }
  }
  gbar(&cnt[1], SORTB);

  // ---- scatter: 3 axes per point ----
  if (gid < n) {
    const float4 v = make_float4(x, y, z, __int_as_float(gid));
    const int px = atomicAdd(&scatCur[bin_of(x)], 1);
    const int py = atomicAdd(&scatCur[NBINS + bin_of(y)], 1);
    const int pz = atomicAdd(&scatCur[2 * NBINS + bin_of(z)], 1);
    s_all[px] = v;
    s_all[n + py] = v;
    s_all[2 * n + pz] = v;
  }
}

// ---------------- K2: query (one wave per query, best-axis extent) -----------
__global__ __launch_bounds__(BLOCK)
void query_kernel(const float4* __restrict__ sx, const float4* __restrict__ sy,
                  const float4* __restrict__ sz, const int* __restrict__ cx,
                  const int* __restrict__ cy, const int* __restrict__ cz,
                  const float* __restrict__ W, const float* __restrict__ bias,
                  float* __restrict__ out, int n) {
  const int lane = threadIdx.x & 63;
  const int wv   = threadIdx.x >> 6;
  const int t    = wv * (n >> 2) + blockIdx.x;     // quartile interleave
  const float W0 = W[0], W1 = W[1], W2 = W[2];
  const float bb = bias[0];

  const float4 me = sx[t];                          // enumerate via x-sorted
  const float xi = me.x, yi = me.y, zi = me.z;
  const int orig = __float_as_int(me.w);

  // ---- choose axis with max |coord| (wave-uniform) ----
  const float ax = fabsf(xi), ay = fabsf(yi), az = fabsf(zi);
  const float4* sv; const int* cur; float cq;
  if (ay >= ax && ay >= az)      { sv = sy; cur = cy; cq = yi; }
  else if (az >= ax && az >= ay) { sv = sz; cur = cz; cq = zi; }
  else                           { sv = sx; cur = cx; cq = xi; }

  // ---- bin-estimated rank -> seed window ----
  const int bq = bin_of(cq);
  const int bs = (bq > 0) ? cur[bq - 1] : 0;
  const int be = cur[bq];
  int lo = ((bs + be) >> 1) - SEED / 2;
  lo = lo < 0 ? 0 : lo;
  lo = lo > n - SEED ? n - SEED : lo;
  const float4* base = sv + lo + lane;

  // ---- 1. seed lane-minima ----
  float m = BIG;
#pragma unroll
  for (int s = 0; s < SEED / 64; ++s) {
    const float4 c = base[s * 64];
    const float dx = xi - c.x, dy = yi - c.y, dz = zi - c.z;
    m = fminf(m, fmaf(dx, dx, fmaf(dy, dy, dz * dz)));
  }

  // ---- 2. u = 12th smallest of the 64 lane minima ----
  float u;
  {
    float v = m;
#pragma unroll
    for (int r = 0; r < KK; ++r) {
      const float mm = wave_min(v);
      u = mm;
      v = (v == mm) ? BIG : v;
    }
  }

  // ---- 3. extent from prefix sums: {|c - cq| <= sqrt(u)} ⊆ [lo2, hi2) ----
  const float s = sqrtf(u);
  const int bl = bin_of(cq - s);
  const int bh = bin_of(cq + s);
  const int lo2 = (bl > 0) ? cur[bl - 1] : 0;
  const int hi2 = cur[bh];
  const int steps = (hi2 - lo2 + 63) >> 6;

  // ---- collect-scan: fixed-trip, break-free ----
  float qd[CD], qw[CD];
  int ccnt = 0;
#pragma unroll
  for (int k = 0; k < CD; ++k) { qd[k] = BIG; qw[k] = 0.f; }

  int st = 0;
  for (; st + 2 <= steps; st += 2) {
    const int p0 = lo2 + st * 64 + lane;
    const int p1 = p0 + 64;
    const float4 c0 = sv[p0];
    const float4 c1 = sv[(p1 < hi2) ? p1 : hi2 - 1];
    {
      const float dx = xi - c0.x, dy = yi - c0.y, dz = zi - c0.z;
      const float d2 = fmaf(dx, dx, fmaf(dy, dy, dz * dz));
      if (d2 <= u) {
        const float w = fmaf(W0, fabsf(dx), fmaf(W1, fabsf(dy), W2 * fabsf(dz)));
        ++ccnt; ins4(qd, qw, d2, w);
      }
    }
    if (p1 < hi2) {
      const float dx = xi - c1.x, dy = yi - c1.y, dz = zi - c1.z;
      const float d2 = fmaf(dx, dx, fmaf(dy, dy, dz * dz));
      if (d2 <= u) {
        const float w = fmaf(W0, fabsf(dx), fmaf(W1, fabsf(dy), W2 * fabsf(dz)));
        ++ccnt; ins4(qd, qw, d2, w);
      }
    }
  }
  for (; st < steps; ++st) {
    const int pos = lo2 + st * 64 + lane;
    if (pos < hi2) {
      const float4 c = sv[pos];
      const float dx = xi - c.x, dy = yi - c.y, dz = zi - c.z;
      const float d2 = fmaf(dx, dx, fmaf(dy, dy, dz * dz));
      if (d2 <= u) {
        const float w = fmaf(W0, fabsf(dx), fmaf(W1, fabsf(dy), W2 * fabsf(dz)));
        ++ccnt; ins4(qd, qw, d2, w);
      }
    }
  }

  // ---- 4. extract exact sum over the 12 smallest ----
  float acc = 0.f;
  const bool ovf = __ballot(ccnt > CD) != 0ULL;   // wave-uniform
  if (!ovf) {
    // total count C and per-lane partial sum of ALL collected w
    int C = ccnt;
#pragma unroll
    for (int o = 1; o < 64; o <<= 1) C += __shfl_xor(C, o);
    acc = qw[0] + qw[1] + qw[2] + qw[3];          // BIG slots carry w=0
    const int r = C - KK;                          // entries to remove (>=0)

    if (r <= 8) {
      // count-down: remove the r largest collected entries (r ~ 1-3)
      for (int it = 0; it < r; ++it) {
        const bool v3 = qd[3] < BIG, v2 = qd[2] < BIG;
        const bool v1 = qd[1] < BIG, v0 = qd[0] < BIG;
        const float mx = v3 ? qd[3] : (v2 ? qd[2] : (v1 ? qd[1] : (v0 ? qd[0] : -1.f)));
        const float wm = wave_max(mx);
        const bool hit = (mx == wm) && (mx >= 0.f);
        const unsigned long long bal = __ballot(hit);
        if (hit && lane == (int)(__ffsll(bal) - 1)) {
          if (v3)      { acc -= qw[3]; qd[3] = BIG; qw[3] = 0.f; }
          else if (v2) { acc -= qw[2]; qd[2] = BIG; qw[2] = 0.f; }
          else if (v1) { acc -= qw[1]; qd[1] = BIG; qw[1] = 0.f; }
          else         { acc -= qw[0]; qd[0] = BIG; qw[0] = 0.f; }
        }
      }
    } else {
      // rare: many ties/cluster -> original 12-round min-select
      acc = 0.f;
#pragma unroll
      for (int rr = 0; rr < KK; ++rr) {
        const float mm = wave_min(qd[0]);
        const unsigned long long bal = __ballot(qd[0] == mm);
        if (qd[0] == mm && lane == (int)(__ffsll(bal) - 1)) {
          acc += qw[0];
#pragma unroll
          for (int k = 0; k < CD - 1; ++k) { qd[k] = qd[k + 1]; qw[k] = qw[k + 1]; }
          qd[CD - 1] = BIG;
        }
      }
    }
  } else {
    // rare exact fallback over the same extent: med3 top-12 -> tau -> rescan
    float dd[KK];
#pragma unroll
    for (int k = 0; k < KK; ++k) dd[k] = BIG;
    for (int s0 = 0; s0 < steps; ++s0) {
      const int pos = lo2 + s0 * 64 + lane;
      const float4 c = sv[(pos < hi2) ? pos : hi2 - 1];
      const float dx = xi - c.x, dy = yi - c.y, dz = zi - c.z;
      const float d2 = (pos < hi2) ? fmaf(dx, dx, fmaf(dy, dy, dz * dz)) : BIG;
#pragma unroll
      for (int k = KK - 1; k >= 1; --k)
        dd[k] = __builtin_amdgcn_fmed3f(d2, dd[k - 1], dd[k]);
      dd[0] = fminf(dd[0], d2);
    }
    float tau = 0.f;
#pragma unroll
    for (int r = 0; r < KK; ++r) {
      const float mm = wave_min(dd[0]);
      if (dd[0] == mm) {
#pragma unroll
        for (int k = 0; k < KK - 1; ++k) dd[k] = dd[k + 1];
        dd[KK - 1] = BIG;
      }
      tau = mm;
    }
    for (int s0 = 0; s0 < steps; ++s0) {
      const int pos = lo2 + s0 * 64 + lane;
      if (pos < hi2) {
        const float4 c = sv[pos];
        const float dx = xi - c.x, dy = yi - c.y, dz = zi - c.z;
        const float d2 = fmaf(dx, dx, fmaf(dy, dy, dz * dz));
        const float w  = fmaf(W0, fabsf(dx), fmaf(W1, fabsf(dy), W2 * fabsf(dz)));
        acc += (d2 <= tau) ? w : 0.f;
      }
    }
  }

  // ---- 5. reduce + write ----
#pragma unroll
  for (int o = 1; o < 64; o <<= 1) acc += __shfl_xor(acc, o);
  if (lane == 0) {
    const float xw0 = W0 * xi + W1 * yi + W2 * zi;
    // 1 + 11/sqrt(2)
    out[orig] = bb + (xw0 * 8.778174593052022f + 0.5f * acc) * (1.0f / 12.0f);
  }
}

extern "C" void kernel_launch(void* const* d_in, const int* in_sizes, int n_in,
                              void* d_out, int out_size, void* d_ws, size_t ws_size,
                              hipStream_t stream) {
  const float* p  = (const float*)d_in[0];
  const float* W  = (const float*)d_in[1];
  const float* bb = (const float*)d_in[2];
  float* out = (float*)d_out;

  const int n = in_sizes[0] / 3;   // 16384

  // ws: hist 3x2048 @0 | cnt[16] @24576 | cursorEnd 3x2048 @24640
  //     | scatCur 3x2048 @49216 | sorted 3xn float4 @73792
  int*    hist      = (int*)d_ws;
  int*    cnt       = (int*)((char*)d_ws + 24576);
  int*    cursorEnd = (int*)((char*)d_ws + 24640);
  int*    scatCur   = (int*)((char*)d_ws + 49216);
  float4* s_all     = (float4*)((char*)d_ws + 73792);

  int*    cx = cursorEnd;
  int*    cy = cx + NBINS;
  int*    cz = cy + NBINS;
  float4* sx = s_all;
  float4* sy = sx + n;
  float4* sz = sy + n;

  hipMemsetAsync(d_ws, 0, 24640, stream);   // hist + cnt
  sort64_kernel<<<SORTB, 256, 0, stream>>>(p, hist, cursorEnd, scatCur, cnt, s_all, n);
  query_kernel<<<n / WPB, BLOCK, 0, stream>>>(sx, sy, sz, cx, cy, cz, W, bb, out, n);
}